// Round 17
// baseline (542.500 us; speedup 1.0000x reference)
//
#include <hip/hip_runtime.h>

#define N_NODES 20000
#define N_EDGES 640000
#define XS 136   // LDS activation row stride in bf16 units (128 + 8 pad)

#define INV_SQRT_AVG 0.0070714082f   // 1/sqrt(19999)
#define INV_AVG      5.000250e-5f    // 1/19999

#define FEATB_OFF 147456             // ushort offset of bf16 feat table in ws (after 9*16384 weights)

typedef __attribute__((ext_vector_type(8))) short bf16x8;
typedef __attribute__((ext_vector_type(4))) float f32x4;
typedef __attribute__((ext_vector_type(2))) _Float16 f16x2;

// Non-draining barrier: LDS ordering only (proven neutral-correct in r11/r12).
#define BAR() asm volatile("s_waitcnt lgkmcnt(0)\n\ts_barrier" ::: "memory")

__device__ __forceinline__ ushort f2b(float f) {
  unsigned x = __float_as_uint(f);
  unsigned r = (x + 0x7fffu + ((x >> 16) & 1u)) >> 16;   // RNE
  return (ushort)r;
}
__device__ __forceinline__ float silu(float v) {
  return v * __builtin_amdgcn_rcpf(1.0f + __expf(-v));
}
__device__ __forceinline__ float sigmoid_fast(float v) {
  return __builtin_amdgcn_rcpf(1.0f + __expf(-v));
}
__device__ __forceinline__ float lo16f(uint u) {   // f16 low half -> f32
  ushort us = (ushort)(u & 0xffffu);
  _Float16 h; __builtin_memcpy(&h, &us, 2);
  return (float)h;
}
__device__ __forceinline__ float hi16f(uint u) {
  ushort us = (ushort)(u >> 16);
  _Float16 h; __builtin_memcpy(&h, &us, 2);
  return (float)h;
}
// native packed f16 atomic add (global_atomic_pk_add_f16, gfx90a+)
__device__ __forceinline__ void pk_atomic_f16(ushort* p, float x, float y) {
  typedef __attribute__((address_space(1))) f16x2 gf2;
  f16x2 v = {(_Float16)x, (_Float16)y};
  __builtin_amdgcn_global_atomic_fadd_v2f16((gf2*)(unsigned long long)p, v);
}

// ---------------- setup1: weights f32[k][n]->bf16[n][k]; feat->bf16; zero outv ----
struct PrepArgs { const float* src[9]; };

__global__ __launch_bounds__(256) void setup_kernel(PrepArgs a,
                                                    const float* __restrict__ feat,
                                                    ushort* __restrict__ wq,
                                                    ushort* __restrict__ featb,
                                                    float* __restrict__ outv) {
  int i = blockIdx.x * 256 + threadIdx.x;
  if (i < 60000) outv[i] = 0.0f;
  if (i < N_NODES * 128) featb[i] = f2b(feat[i]);
  if (i < 9 * 16384) {
    int m = i >> 14, idx = i & 16383;
    int k = idx >> 7, n = idx & 127;
    wq[m * 16384 + n * 128 + k] = f2b(a.src[m][k * 128 + n]);
  }
}

// ---------------- setup2: zero the f16 m_acc (overlays the consumed feat input) ----
__global__ __launch_bounds__(256) void zero_macc_kernel(uint* __restrict__ m_acc32) {
  int i = blockIdx.x * 256 + threadIdx.x;   // 1.28M uints = 5.12MB
  m_acc32[i] = 0u;
}

// ---------------- MFMA per-wave 32x64x128: 2x2 split of the 64x128 tile ----
// Wave handles rows [mb,mb+32) x cols [nb,nb+64). A-reads halved vs the
// old M64xN32 split (8 ds_read_b128/gemm); B-loads doubled (16, L1-hot),
// batched in ct-pairs to bound VGPR.
__device__ __forceinline__ void gemm22(const ushort* X, int mb,
                                       const ushort* __restrict__ Wn,
                                       int c, int q, f32x4 acc[2][4]) {
  const int kq = q * 8;
  bf16x8 a[2][4];
#pragma unroll
  for (int mt = 0; mt < 2; ++mt)
#pragma unroll
    for (int ks = 0; ks < 4; ++ks)
      a[mt][ks] = *(const bf16x8*)(X + (mb + mt * 16 + c) * XS + ks * 32 + kq);
#pragma unroll
  for (int cp = 0; cp < 2; ++cp) {
    bf16x8 b[2][4];
#pragma unroll
    for (int ctl = 0; ctl < 2; ++ctl)
#pragma unroll
      for (int ks = 0; ks < 4; ++ks)
        b[ctl][ks] = *(const bf16x8*)(Wn + ((cp * 2 + ctl) * 16 + c) * 128 + ks * 32 + kq);
#pragma unroll
    for (int mt = 0; mt < 2; ++mt)
#pragma unroll
      for (int ks = 0; ks < 4; ++ks) {
        acc[mt][cp * 2 + 0] = __builtin_amdgcn_mfma_f32_16x16x32_bf16(a[mt][ks], b[0][ks], acc[mt][cp * 2 + 0], 0, 0, 0);
        acc[mt][cp * 2 + 1] = __builtin_amdgcn_mfma_f32_16x16x32_bf16(a[mt][ks], b[1][ks], acc[mt][cp * 2 + 1], 0, 0, 0);
      }
  }
}

__device__ __forceinline__ void zero24(f32x4 acc[2][4]) {
  const f32x4 z4 = {0.f, 0.f, 0.f, 0.f};
#pragma unroll
  for (int mt = 0; mt < 2; ++mt)
#pragma unroll
    for (int ct = 0; ct < 4; ++ct) acc[mt][ct] = z4;
}

// half-height gemm for the 32-node node kernel (unchanged r16 structure)
__device__ __forceinline__ void gemm2_m32(const ushort* X, const ushort* __restrict__ Wn0,
                                          int c, int q, f32x4 acc[2][2]) {
  const int kq = q * 8;
  bf16x8 b[2][4];
#pragma unroll
  for (int ct = 0; ct < 2; ++ct)
#pragma unroll
    for (int ks = 0; ks < 4; ++ks)
      b[ct][ks] = *(const bf16x8*)(Wn0 + (ct * 16 + c) * 128 + ks * 32 + kq);
#pragma unroll
  for (int mt = 0; mt < 2; ++mt)
#pragma unroll
    for (int ks = 0; ks < 4; ++ks) {
      bf16x8 a = *(const bf16x8*)(X + (mt * 16 + c) * XS + ks * 32 + kq);
      acc[mt][0] = __builtin_amdgcn_mfma_f32_16x16x32_bf16(a, b[0][ks], acc[mt][0], 0, 0, 0);
      acc[mt][1] = __builtin_amdgcn_mfma_f32_16x16x32_bf16(a, b[1][ks], acc[mt][1], 0, 0, 0);
    }
}

// stage one bf16 row from global into LDS (4 threads/row, 16B chunks)
__device__ __forceinline__ void stage_copy(ushort* X, const ushort* __restrict__ src,
                                           int row, int sub) {
  const bf16x8* s = (const bf16x8*)src;
  bf16x8* d = (bf16x8*)(X + row * XS);
#pragma unroll
  for (int c2 = 0; c2 < 4; ++c2) d[sub + 4 * c2] = s[sub + 4 * c2];
}

// stage one f16 row (scaled) as bf16 into LDS (4 threads/row)
__device__ __forceinline__ void stage_cvt_f16(ushort* X, const ushort* __restrict__ src,
                                              int row, int sub, float scale) {
  const uint4* s4 = (const uint4*)src + sub * 4;   // 4 x 16B = 64B per thread
  uint* d = (uint*)(X + row * XS + sub * 32);
#pragma unroll
  for (int i = 0; i < 4; ++i) {
    uint4 v = s4[i];
    uint u[4] = {v.x, v.y, v.z, v.w};
#pragma unroll
    for (int j = 0; j < 4; ++j) {
      float x = lo16f(u[j]) * scale, y = hi16f(u[j]) * scale;
      d[4 * i + j] = (unsigned)f2b(x) | ((unsigned)f2b(y) << 16);
    }
  }
}

// ---------------- edge kernel: single buffer, 2x2 wave split, f16 packed atomics ----
__global__ __launch_bounds__(256, 4) void edge_kernel(
    const float* __restrict__ pos, const ushort* __restrict__ featb,
    const int* __restrict__ snd, const int* __restrict__ rcv,
    const ushort* __restrict__ wq,
    const float* __restrict__ pe_w0, const float* __restrict__ pe_b0,
    const float* __restrict__ pe_b1,
    const float* __restrict__ px_b0, const float* __restrict__ px_b1,
    const float* __restrict__ px_out_w, const float* __restrict__ px_out_b,
    const float* __restrict__ e_w, const float* __restrict__ e_b,
    float* __restrict__ outv, ushort* __restrict__ outm) {
  __shared__ ushort XA[64 * XS];
  __shared__ float lenf[64], gp[64], pp[64], egl[64];
  __shared__ float vec3[64][3];
  __shared__ int erc[64];

  const int tid = threadIdx.x;
  const int e0 = blockIdx.x * 64;
  const int lane = tid & 63;
  const int wv = tid >> 6;
  const int c = lane & 15, q = lane >> 4;
  const int nb = (wv & 1) * 64;    // N-half
  const int mb = (wv >> 1) * 32;   // M-half

  if (tid < 64) {
    int s = snd[e0 + tid], r = rcv[e0 + tid];
    erc[tid] = r;
    float vx = pos[r * 3 + 0] - pos[s * 3 + 0];
    float vy = pos[r * 3 + 1] - pos[s * 3 + 1];
    float vz = pos[r * 3 + 2] - pos[s * 3 + 2];
    float n2 = vx * vx + vy * vy + vz * vz;
    float L = (n2 > 0.0f) ? sqrtf(n2) : 0.0f;
    vec3[tid][0] = vx; vec3[tid][1] = vy; vec3[tid][2] = vz;
    lenf[tid] = L; gp[tid] = 0.0f; pp[tid] = 0.0f;
  }
  {
    int row = tid >> 2, sub = tid & 3;
    stage_copy(XA, featb + (size_t)snd[e0 + row] * 128, row, sub);
  }
  BAR();

  int rowr[2][4];
  float lenr[2][4];
#pragma unroll
  for (int mt = 0; mt < 2; ++mt)
#pragma unroll
    for (int rg = 0; rg < 4; ++rg) {
      rowr[mt][rg] = mb + mt * 16 + q * 4 + rg;
      lenr[mt][rg] = lenf[rowr[mt][rg]];
    }

  f32x4 acc[2][4];
  zero24(acc);

  // ---- phi_e layer 0a: sender half ----
  gemm22(XA, mb, wq + 0 * 16384 + nb * 128, c, q, acc);
  BAR();   // all waves done reading sender rows
  {
    int row = tid >> 2, sub = tid & 3;
    stage_copy(XA, featb + (size_t)rcv[e0 + row] * 128, row, sub);
  }
  BAR();
  // ---- phi_e layer 0b: receiver half ----
  gemm22(XA, mb, wq + 1 * 16384 + nb * 128, c, q, acc);
  BAR();   // done reading receiver rows before h0 overwrite
#pragma unroll
  for (int ct = 0; ct < 4; ++ct) {
    int col = nb + ct * 16 + c;
    float w0 = pe_w0[256 * 128 + col], b0 = pe_b0[col];
#pragma unroll
    for (int mt = 0; mt < 2; ++mt)
#pragma unroll
      for (int rg = 0; rg < 4; ++rg)
        XA[rowr[mt][rg] * XS + col] = f2b(silu(acc[mt][ct][rg] + lenr[mt][rg] * w0 + b0));
  }
  BAR();

  // ---- phi_e layer 1: XA(h0) -> m (held in acc), gate partials ----
  zero24(acc);
  gemm22(XA, mb, wq + 2 * 16384 + nb * 128, c, q, acc);
  {
    float rp[2][4] = {{0.f, 0.f, 0.f, 0.f}, {0.f, 0.f, 0.f, 0.f}};
#pragma unroll
    for (int ct = 0; ct < 4; ++ct) {
      int col = nb + ct * 16 + c;
      float b1 = pe_b1[col], ew = e_w[col];
#pragma unroll
      for (int mt = 0; mt < 2; ++mt)
#pragma unroll
        for (int rg = 0; rg < 4; ++rg) {
          float m = silu(acc[mt][ct][rg] + b1);
          acc[mt][ct][rg] = m;
          rp[mt][rg] += m * ew;
        }
    }
#pragma unroll
    for (int mt = 0; mt < 2; ++mt)
#pragma unroll
      for (int rg = 0; rg < 4; ++rg) {
        float s = rp[mt][rg];
        s += __shfl_xor(s, 1); s += __shfl_xor(s, 2);
        s += __shfl_xor(s, 4); s += __shfl_xor(s, 8);
        if (c == 0) atomicAdd(&gp[rowr[mt][rg]], s);
      }
  }
  BAR();   // all waves done reading h0; gp complete
  // write m -> XA (bf16); gate from gp
#pragma unroll
  for (int ct = 0; ct < 4; ++ct) {
    int col = nb + ct * 16 + c;
#pragma unroll
    for (int mt = 0; mt < 2; ++mt)
#pragma unroll
      for (int rg = 0; rg < 4; ++rg)
        XA[rowr[mt][rg] * XS + col] = f2b(acc[mt][ct][rg]);
  }
  if (tid < 64) egl[tid] = sigmoid_fast(gp[tid] + e_b[0]);
  BAR();   // m (bf16) + egl visible

  // ---- gated m_i PACKED f16 atomics: 4 rows x 1 cacheline per instruction ----
  {
    int j = lane & 15, rr = lane >> 4;
#pragma unroll
    for (int rg = 0; rg < 4; ++rg) {
      int row = wv * 16 + rg * 4 + rr;
      float eg = egl[row];
      ushort* dst = outm + (size_t)erc[row] * 128;
      const uint* src = (const uint*)(XA + row * XS);
#pragma unroll
      for (int ch = 0; ch < 4; ++ch) {
        uint u = src[ch * 16 + j];
        float x = __uint_as_float(u << 16) * eg;           // bf16 lo
        float y = __uint_as_float(u & 0xffff0000u) * eg;   // bf16 hi
        pk_atomic_f16(dst + (ch * 16 + j) * 2, x, y);
      }
    }
  }

  // ---- phi_x layer 0: XA(m) -> acc (atomics above stay in flight) ----
  zero24(acc);
  gemm22(XA, mb, wq + 3 * 16384 + nb * 128, c, q, acc);
  BAR();   // done reading m before px0-act overwrite
#pragma unroll
  for (int ct = 0; ct < 4; ++ct) {
    int col = nb + ct * 16 + c;
    float b0 = px_b0[col];
#pragma unroll
    for (int mt = 0; mt < 2; ++mt)
#pragma unroll
      for (int rg = 0; rg < 4; ++rg)
        XA[rowr[mt][rg] * XS + col] = f2b(silu(acc[mt][ct][rg] + b0));
  }
  BAR();

  // ---- phi_x layer 1: XA -> Dense(1) tail ----
  zero24(acc);
  gemm22(XA, mb, wq + 4 * 16384 + nb * 128, c, q, acc);
  {
    float sp[2][4] = {{0.f, 0.f, 0.f, 0.f}, {0.f, 0.f, 0.f, 0.f}};
#pragma unroll
    for (int ct = 0; ct < 4; ++ct) {
      int col = nb + ct * 16 + c;
      float b1 = px_b1[col], pw = px_out_w[col];
#pragma unroll
      for (int mt = 0; mt < 2; ++mt)
#pragma unroll
        for (int rg = 0; rg < 4; ++rg)
          sp[mt][rg] += silu(acc[mt][ct][rg] + b1) * pw;
    }
#pragma unroll
    for (int mt = 0; mt < 2; ++mt)
#pragma unroll
      for (int rg = 0; rg < 4; ++rg) {
        float s = sp[mt][rg];
        s += __shfl_xor(s, 1); s += __shfl_xor(s, 2);
        s += __shfl_xor(s, 4); s += __shfl_xor(s, 8);
        if (c == 0) atomicAdd(&pp[rowr[mt][rg]], s);
      }
  }
  BAR();
  if (tid < 192) {
    int ee = tid / 3, cc = tid - ee * 3;
    float phi = pp[ee] + px_out_b[0];
    float sh = phi * vec3[ee][cc] * __builtin_amdgcn_rcpf(1.0f + lenf[ee]);
    atomicAdd(&outv[(size_t)erc[ee] * 3 + cc], sh);
  }
}

// ---------------- node kernel: 32-node tiles (625 blocks), f16 m_acc in ----------------
__global__ __launch_bounds__(256, 5) void node_kernel(
    const float* __restrict__ pos,
    const ushort* __restrict__ featb, const ushort* __restrict__ wq,
    const ushort* __restrict__ outm,
    const float* __restrict__ ph_b0, const float* __restrict__ ph_b1,
    const float* __restrict__ ph_b2,
    float* __restrict__ outv, float* __restrict__ outf) {
  __shared__ ushort XA[32 * XS];
  __shared__ ushort XB[32 * XS];

  const int tid = threadIdx.x;
  const int nb0 = blockIdx.x * 32;
  const int lane = tid & 63;
  const int wv = tid >> 6;
  const int c = lane & 15, q = lane >> 4;
  const int n0 = wv * 32;
  const int col0 = n0 + c, col1 = col0 + 16;

  if (tid < 128) {
    int row = tid >> 2, sub = tid & 3;
    int nn = nb0 + row; if (nn >= N_NODES) nn = N_NODES - 1;
    stage_cvt_f16(XA, outm + (size_t)nn * 128, row, sub, INV_SQRT_AVG);  // m_i (f16)
    stage_copy(XB, featb + (size_t)nn * 128, row, sub);
  }
  BAR();

  const f32x4 z4 = {0.f, 0.f, 0.f, 0.f};
  f32x4 acc[2][2];
#pragma unroll
  for (int mt = 0; mt < 2; ++mt) { acc[mt][0] = z4; acc[mt][1] = z4; }

  // ---- ph layer 0: [m_i | feat] ----
  gemm2_m32(XA, wq + 5 * 16384 + n0 * 128, c, q, acc);
  gemm2_m32(XB, wq + 6 * 16384 + n0 * 128, c, q, acc);
  BAR();
  {
    float b0 = ph_b0[col0], b1 = ph_b0[col1];
#pragma unroll
    for (int mt = 0; mt < 2; ++mt)
#pragma unroll
      for (int rg = 0; rg < 4; ++rg) {
        int row = mt * 16 + q * 4 + rg;
        XA[row * XS + col0] = f2b(silu(acc[mt][0][rg] + b0));
        XA[row * XS + col1] = f2b(silu(acc[mt][1][rg] + b1));
      }
  }
  BAR();

  // ---- ph layer 1: XA -> XA (XB keeps feat for residual) ----
#pragma unroll
  for (int mt = 0; mt < 2; ++mt) { acc[mt][0] = z4; acc[mt][1] = z4; }
  gemm2_m32(XA, wq + 7 * 16384 + n0 * 128, c, q, acc);
  BAR();
  {
    float b0 = ph_b1[col0], b1 = ph_b1[col1];
#pragma unroll
    for (int mt = 0; mt < 2; ++mt)
#pragma unroll
      for (int rg = 0; rg < 4; ++rg) {
        int row = mt * 16 + q * 4 + rg;
        XA[row * XS + col0] = f2b(silu(acc[mt][0][rg] + b0));
        XA[row * XS + col1] = f2b(silu(acc[mt][1][rg] + b1));
      }
  }
  BAR();

  // ---- ph layer 2 (no act) + residual from XB(featb) ----
#pragma unroll
  for (int mt = 0; mt < 2; ++mt) { acc[mt][0] = z4; acc[mt][1] = z4; }
  gemm2_m32(XA, wq + 8 * 16384 + n0 * 128, c, q, acc);
  {
    float b0 = ph_b2[col0], b1 = ph_b2[col1];
#pragma unroll
    for (int mt = 0; mt < 2; ++mt)
#pragma unroll
      for (int rg = 0; rg < 4; ++rg) {
        int row = mt * 16 + q * 4 + rg;
        int nn = nb0 + row;
        if (nn < N_NODES) {
          size_t o = (size_t)nn * 128;
          float r0 = __uint_as_float(((uint)XB[row * XS + col0]) << 16);
          float r1 = __uint_as_float(((uint)XB[row * XS + col1]) << 16);
          outf[o + col0] = acc[mt][0][rg] + b0 + r0;
          outf[o + col1] = acc[mt][1][rg] + b1 + r1;
        }
      }
  }
  if (tid < 96) {
    int nl = tid / 3, cc = tid - nl * 3;
    int nn = nb0 + nl;
    if (nn < N_NODES)
      outv[nn * 3 + cc] = pos[nn * 3 + cc] + outv[nn * 3 + cc] * INV_AVG;
  }
}

// ---------------- launch ----------------
extern "C" void kernel_launch(void* const* d_in, const int* in_sizes, int n_in,
                              void* d_out, int out_size, void* d_ws, size_t ws_size,
                              hipStream_t stream) {
  const float* pos  = (const float*)d_in[0];
  const float* feat = (const float*)d_in[1];
  const float* pe_w0 = (const float*)d_in[2];
  const float* pe_b0 = (const float*)d_in[3];
  const float* pe_b1 = (const float*)d_in[5];
  const float* px_b0 = (const float*)d_in[7];
  const float* px_b1 = (const float*)d_in[9];
  const float* px_out_w = (const float*)d_in[10];
  const float* px_out_b = (const float*)d_in[11];
  const float* e_w = (const float*)d_in[12];
  const float* e_b = (const float*)d_in[13];
  const float* ph_b0 = (const float*)d_in[15];
  const float* ph_b1 = (const float*)d_in[17];
  const float* ph_b2 = (const float*)d_in[19];
  const int* snd = (const int*)d_in[20];
  const int* rcv = (const int*)d_in[21];
  ushort* wq = (ushort*)d_ws;
  ushort* featb = wq + FEATB_OFF;
  float* out = (float*)d_out;
  // after setup consumes feat, its buffer becomes the f16 m_i accumulator
  ushort* outm = (ushort*)d_in[1];

  PrepArgs a;
  a.src[0] = pe_w0;
  a.src[1] = pe_w0 + 128 * 128;
  a.src[2] = (const float*)d_in[4];               // pe_w1
  a.src[3] = (const float*)d_in[6];               // px_w0
  a.src[4] = (const float*)d_in[8];               // px_w1
  a.src[5] = (const float*)d_in[14];              // ph_w0 (m_i half)
  a.src[6] = (const float*)d_in[14] + 128 * 128;  // ph_w0 (feat half)
  a.src[7] = (const float*)d_in[16];              // ph_w1
  a.src[8] = (const float*)d_in[18];              // ph_w2

  // setup1: weight cvt + feat cvt + zero outv (reads all of feat)
  setup_kernel<<<(N_NODES * 128) / 256, 256, 0, stream>>>(a, feat, wq, featb, out);
  // setup2 (stream-ordered after setup1): zero f16 m_acc overlaying feat
  zero_macc_kernel<<<(N_NODES * 128 / 2) / 256, 256, 0, stream>>>((uint*)outm);

  edge_kernel<<<N_EDGES / 64, 256, 0, stream>>>(
      pos, featb, snd, rcv, wq,
      pe_w0, pe_b0, pe_b1, px_b0, px_b1,
      px_out_w, px_out_b, e_w, e_b,
      out, outm);

  node_kernel<<<(N_NODES + 31) / 32, 256, 0, stream>>>(
      pos, featb, wq, outm, ph_b0, ph_b1, ph_b2,
      out, out + 60000);
}

// Round 18
// 397.929 us; speedup vs baseline: 1.3633x; 1.3633x over previous
//
#include <hip/hip_runtime.h>

#define N_NODES 20000
#define N_EDGES 640000
#define XS 136   // LDS activation row stride in bf16 units (128 + 8 pad)

#define INV_SQRT_AVG 0.0070714082f   // 1/sqrt(19999)
#define INV_AVG      5.000250e-5f    // 1/19999

#define FEATB_OFF 147456             // ushort offset of bf16 feat table in ws (after 9*16384 weights)

typedef __attribute__((ext_vector_type(8))) short bf16x8;
typedef __attribute__((ext_vector_type(4))) float f32x4;
typedef __attribute__((ext_vector_type(2))) _Float16 f16x2;

// Non-draining barrier: LDS ordering only (proven neutral-correct in r11/r12).
#define BAR() asm volatile("s_waitcnt lgkmcnt(0)\n\ts_barrier" ::: "memory")

__device__ __forceinline__ ushort f2b(float f) {
  unsigned x = __float_as_uint(f);
  unsigned r = (x + 0x7fffu + ((x >> 16) & 1u)) >> 16;   // RNE
  return (ushort)r;
}
__device__ __forceinline__ float silu(float v) {
  return v * __builtin_amdgcn_rcpf(1.0f + __expf(-v));
}
__device__ __forceinline__ float sigmoid_fast(float v) {
  return __builtin_amdgcn_rcpf(1.0f + __expf(-v));
}
__device__ __forceinline__ float lo16f(uint u) {   // f16 low half -> f32
  ushort us = (ushort)(u & 0xffffu);
  _Float16 h; __builtin_memcpy(&h, &us, 2);
  return (float)h;
}
__device__ __forceinline__ float hi16f(uint u) {
  ushort us = (ushort)(u >> 16);
  _Float16 h; __builtin_memcpy(&h, &us, 2);
  return (float)h;
}
// native packed f16 atomic add (global_atomic_pk_add_f16, gfx90a+)
__device__ __forceinline__ void pk_atomic_f16(ushort* p, float x, float y) {
  typedef __attribute__((address_space(1))) f16x2 gf2;
  f16x2 v = {(_Float16)x, (_Float16)y};
  __builtin_amdgcn_global_atomic_fadd_v2f16((gf2*)(unsigned long long)p, v);
}

// ---------------- setup: weights f32[k][n]->bf16[n][k]; feat->bf16; zero m_acc/outv ----
// feat and the f16 m_acc alias (same buffer): thread i reads feat[i] (bytes
// 4i..4i+3) then zeroes those same bytes (m_acc uint slot i, for i < 1.28M).
// Same-thread read->write ordering is the only dependency (r14/r15-proven).
struct PrepArgs { const float* src[9]; };

__global__ __launch_bounds__(256) void setup_kernel(PrepArgs a,
                                                    const float* feat,
                                                    ushort* __restrict__ wq,
                                                    ushort* __restrict__ featb,
                                                    uint* m_acc32,
                                                    float* __restrict__ outv) {
  int i = blockIdx.x * 256 + threadIdx.x;
  if (i < 60000) outv[i] = 0.0f;
  float fv = feat[i];
  featb[i] = f2b(fv);
  if (i < N_NODES * 64) m_acc32[i] = 0u;   // zero f16 m_acc (first 5.12 MB)
  if (i < 9 * 16384) {
    int m = i >> 14, idx = i & 16383;
    int k = idx >> 7, n = idx & 127;
    wq[m * 16384 + n * 128 + k] = f2b(a.src[m][k * 128 + n]);
  }
}

// ---------------- MFMA 64x32x128 per wave ----------------
__device__ __forceinline__ void gemm2(const ushort* X, const ushort* __restrict__ Wn0,
                                      int c, int q, f32x4 acc[4][2]) {
  const int kq = q * 8;
  bf16x8 b[2][4];
#pragma unroll
  for (int ct = 0; ct < 2; ++ct)
#pragma unroll
    for (int ks = 0; ks < 4; ++ks)
      b[ct][ks] = *(const bf16x8*)(Wn0 + (ct * 16 + c) * 128 + ks * 32 + kq);
#pragma unroll
  for (int mt = 0; mt < 4; ++mt)
#pragma unroll
    for (int ks = 0; ks < 4; ++ks) {
      bf16x8 a = *(const bf16x8*)(X + (mt * 16 + c) * XS + ks * 32 + kq);
      acc[mt][0] = __builtin_amdgcn_mfma_f32_16x16x32_bf16(a, b[0][ks], acc[mt][0], 0, 0, 0);
      acc[mt][1] = __builtin_amdgcn_mfma_f32_16x16x32_bf16(a, b[1][ks], acc[mt][1], 0, 0, 0);
    }
}

// stage one bf16 row from global into LDS (4 threads/row, 16B chunks)
__device__ __forceinline__ void stage_copy(ushort* X, const ushort* __restrict__ src,
                                           int row, int sub) {
  const bf16x8* s = (const bf16x8*)src;
  bf16x8* d = (bf16x8*)(X + row * XS);
#pragma unroll
  for (int c2 = 0; c2 < 4; ++c2) d[sub + 4 * c2] = s[sub + 4 * c2];
}

// stage one f16 row (scaled) as bf16 into LDS (4 threads/row)
__device__ __forceinline__ void stage_cvt_f16(ushort* X, const ushort* __restrict__ src,
                                              int row, int sub, float scale) {
  const uint4* s4 = (const uint4*)src + sub * 4;   // 4 x 16B = 64B per thread
  uint* d = (uint*)(X + row * XS + sub * 32);
#pragma unroll
  for (int i = 0; i < 4; ++i) {
    uint4 v = s4[i];
    uint u[4] = {v.x, v.y, v.z, v.w};
#pragma unroll
    for (int j = 0; j < 4; ++j) {
      float x = lo16f(u[j]) * scale, y = hi16f(u[j]) * scale;
      d[4 * i + j] = (unsigned)f2b(x) | ((unsigned)f2b(y) << 16);
    }
  }
}

// ---------------- edge kernel: single activation buffer, f16 packed m_i atomics ----
__global__ __launch_bounds__(256, 5) void edge_kernel(
    const float* __restrict__ pos, const ushort* __restrict__ featb,
    const int* __restrict__ snd, const int* __restrict__ rcv,
    const ushort* __restrict__ wq,
    const float* __restrict__ pe_w0, const float* __restrict__ pe_b0,
    const float* __restrict__ pe_b1,
    const float* __restrict__ px_b0, const float* __restrict__ px_b1,
    const float* __restrict__ px_out_w, const float* __restrict__ px_out_b,
    const float* __restrict__ e_w, const float* __restrict__ e_b,
    float* __restrict__ outv, ushort* __restrict__ outm) {
  __shared__ ushort XA[64 * XS];
  __shared__ float lenf[64], gp[64], pp[64], egl[64];
  __shared__ float vec3[64][3];
  __shared__ int erc[64];

  const int tid = threadIdx.x;
  const int e0 = blockIdx.x * 64;
  const int lane = tid & 63;
  const int wv = tid >> 6;
  const int c = lane & 15, q = lane >> 4;
  const int n0 = wv * 32;
  const int col0 = n0 + c, col1 = col0 + 16;

  if (tid < 64) {
    int s = snd[e0 + tid], r = rcv[e0 + tid];
    erc[tid] = r;
    float vx = pos[r * 3 + 0] - pos[s * 3 + 0];
    float vy = pos[r * 3 + 1] - pos[s * 3 + 1];
    float vz = pos[r * 3 + 2] - pos[s * 3 + 2];
    float n2 = vx * vx + vy * vy + vz * vz;
    float L = (n2 > 0.0f) ? sqrtf(n2) : 0.0f;
    vec3[tid][0] = vx; vec3[tid][1] = vy; vec3[tid][2] = vz;
    lenf[tid] = L; gp[tid] = 0.0f; pp[tid] = 0.0f;
  }
  {
    int row = tid >> 2, sub = tid & 3;
    stage_copy(XA, featb + (size_t)snd[e0 + row] * 128, row, sub);
  }
  BAR();

  const f32x4 z4 = {0.f, 0.f, 0.f, 0.f};
  f32x4 acc[4][2];
#pragma unroll
  for (int mt = 0; mt < 4; ++mt) { acc[mt][0] = z4; acc[mt][1] = z4; }

  // ---- phi_e layer 0a: sender half ----
  gemm2(XA, wq + 0 * 16384 + n0 * 128, c, q, acc);
  BAR();
  {
    int row = tid >> 2, sub = tid & 3;
    stage_copy(XA, featb + (size_t)rcv[e0 + row] * 128, row, sub);
  }
  BAR();
  // ---- phi_e layer 0b: receiver half ----
  gemm2(XA, wq + 1 * 16384 + n0 * 128, c, q, acc);
  BAR();
  {
    float b0 = pe_b0[col0], b1 = pe_b0[col1];
    float w0 = pe_w0[256 * 128 + col0], w1 = pe_w0[256 * 128 + col1];
#pragma unroll
    for (int mt = 0; mt < 4; ++mt)
#pragma unroll
      for (int rg = 0; rg < 4; ++rg) {
        int row = mt * 16 + q * 4 + rg;
        float L = lenf[row];
        XA[row * XS + col0] = f2b(silu(acc[mt][0][rg] + L * w0 + b0));
        XA[row * XS + col1] = f2b(silu(acc[mt][1][rg] + L * w1 + b1));
      }
  }
  BAR();

  // ---- phi_e layer 1: XA(h0) -> m, gate partials ----
#pragma unroll
  for (int mt = 0; mt < 4; ++mt) { acc[mt][0] = z4; acc[mt][1] = z4; }
  gemm2(XA, wq + 2 * 16384 + n0 * 128, c, q, acc);
  {
    float b0 = pe_b1[col0], b1 = pe_b1[col1];
    float ew0 = e_w[col0], ew1 = e_w[col1];
#pragma unroll
    for (int mt = 0; mt < 4; ++mt)
#pragma unroll
      for (int rg = 0; rg < 4; ++rg) {
        float m0 = silu(acc[mt][0][rg] + b0);
        float m1 = silu(acc[mt][1][rg] + b1);
        acc[mt][0][rg] = m0;
        acc[mt][1][rg] = m1;
        float rp = m0 * ew0 + m1 * ew1;
        rp += __shfl_xor(rp, 1); rp += __shfl_xor(rp, 2);
        rp += __shfl_xor(rp, 4); rp += __shfl_xor(rp, 8);
        if (c == 0) atomicAdd(&gp[mt * 16 + q * 4 + rg], rp);
      }
  }
  BAR();   // all waves done reading h0; gp complete
  {
#pragma unroll
    for (int mt = 0; mt < 4; ++mt)
#pragma unroll
      for (int rg = 0; rg < 4; ++rg) {
        int row = mt * 16 + q * 4 + rg;
        XA[row * XS + col0] = f2b(acc[mt][0][rg]);
        XA[row * XS + col1] = f2b(acc[mt][1][rg]);
      }
  }
  if (tid < 64) egl[tid] = sigmoid_fast(gp[tid] + e_b[0]);
  BAR();   // m (bf16) + egl visible

  // ---- gated m_i PACKED f16 atomics: 4 rows x 1 cacheline per instruction ----
  {
    int j = lane & 15, rr = lane >> 4;
#pragma unroll
    for (int rg = 0; rg < 4; ++rg) {
      int row = wv * 16 + rg * 4 + rr;
      float eg = egl[row];
      ushort* dst = outm + (size_t)erc[row] * 128;
      const uint* src = (const uint*)(XA + row * XS);
#pragma unroll
      for (int ch = 0; ch < 4; ++ch) {
        uint u = src[ch * 16 + j];
        float x = __uint_as_float(u << 16) * eg;           // bf16 lo
        float y = __uint_as_float(u & 0xffff0000u) * eg;   // bf16 hi
        pk_atomic_f16(dst + (ch * 16 + j) * 2, x, y);
      }
    }
  }

  // ---- phi_x layer 0: XA(m) -> acc (atomics above stay in flight) ----
#pragma unroll
  for (int mt = 0; mt < 4; ++mt) { acc[mt][0] = z4; acc[mt][1] = z4; }
  gemm2(XA, wq + 3 * 16384 + n0 * 128, c, q, acc);
  BAR();
  {
    float b0 = px_b0[col0], b1 = px_b0[col1];
#pragma unroll
    for (int mt = 0; mt < 4; ++mt)
#pragma unroll
      for (int rg = 0; rg < 4; ++rg) {
        int row = mt * 16 + q * 4 + rg;
        XA[row * XS + col0] = f2b(silu(acc[mt][0][rg] + b0));
        XA[row * XS + col1] = f2b(silu(acc[mt][1][rg] + b1));
      }
  }
  BAR();

  // ---- phi_x layer 1: XA -> Dense(1) tail ----
#pragma unroll
  for (int mt = 0; mt < 4; ++mt) { acc[mt][0] = z4; acc[mt][1] = z4; }
  gemm2(XA, wq + 4 * 16384 + n0 * 128, c, q, acc);
  {
    float b0 = px_b1[col0], b1 = px_b1[col1];
    float pw0 = px_out_w[col0], pw1 = px_out_w[col1];
#pragma unroll
    for (int mt = 0; mt < 4; ++mt)
#pragma unroll
      for (int rg = 0; rg < 4; ++rg) {
        float rp = silu(acc[mt][0][rg] + b0) * pw0 + silu(acc[mt][1][rg] + b1) * pw1;
        rp += __shfl_xor(rp, 1); rp += __shfl_xor(rp, 2);
        rp += __shfl_xor(rp, 4); rp += __shfl_xor(rp, 8);
        if (c == 0) atomicAdd(&pp[mt * 16 + q * 4 + rg], rp);
      }
  }
  BAR();
  if (tid < 192) {
    int ee = tid / 3, cc = tid - ee * 3;
    float phi = pp[ee] + px_out_b[0];
    float sh = phi * vec3[ee][cc] * __builtin_amdgcn_rcpf(1.0f + lenf[ee]);
    atomicAdd(&outv[(size_t)erc[ee] * 3 + cc], sh);
  }
}

// ---------------- node kernel: 64-node tiles, f16 m_acc in, residual from featb ----------------
__global__ __launch_bounds__(256, 3) void node_kernel(
    const float* __restrict__ pos,
    const ushort* __restrict__ featb, const ushort* __restrict__ wq,
    const ushort* __restrict__ outm,
    const float* __restrict__ ph_b0, const float* __restrict__ ph_b1,
    const float* __restrict__ ph_b2,
    float* __restrict__ outv, float* __restrict__ outf) {
  __shared__ ushort XA[64 * XS];
  __shared__ ushort XB[64 * XS];

  const int tid = threadIdx.x;
  const int nb0 = blockIdx.x * 64;
  const int lane = tid & 63;
  const int wv = tid >> 6;
  const int c = lane & 15, q = lane >> 4;
  const int n0 = wv * 32;
  const int col0 = n0 + c, col1 = col0 + 16;

  {
    int row = tid >> 2, sub = tid & 3;
    int nn = nb0 + row; if (nn >= N_NODES) nn = N_NODES - 1;
    stage_cvt_f16(XA, outm + (size_t)nn * 128, row, sub, INV_SQRT_AVG);  // m_i (f16)
    stage_copy(XB, featb + (size_t)nn * 128, row, sub);
  }
  BAR();

  const f32x4 z4 = {0.f, 0.f, 0.f, 0.f};
  f32x4 acc[4][2];
#pragma unroll
  for (int mt = 0; mt < 4; ++mt) { acc[mt][0] = z4; acc[mt][1] = z4; }

  // ---- ph layer 0: [m_i | feat] ----
  gemm2(XA, wq + 5 * 16384 + n0 * 128, c, q, acc);
  gemm2(XB, wq + 6 * 16384 + n0 * 128, c, q, acc);
  BAR();
  {
    float b0 = ph_b0[col0], b1 = ph_b0[col1];
#pragma unroll
    for (int mt = 0; mt < 4; ++mt)
#pragma unroll
      for (int rg = 0; rg < 4; ++rg) {
        int row = mt * 16 + q * 4 + rg;
        XA[row * XS + col0] = f2b(silu(acc[mt][0][rg] + b0));
        XA[row * XS + col1] = f2b(silu(acc[mt][1][rg] + b1));
      }
  }
  BAR();

  // ---- ph layer 1: XA -> XA (XB keeps feat for residual) ----
#pragma unroll
  for (int mt = 0; mt < 4; ++mt) { acc[mt][0] = z4; acc[mt][1] = z4; }
  gemm2(XA, wq + 7 * 16384 + n0 * 128, c, q, acc);
  BAR();
  {
    float b0 = ph_b1[col0], b1 = ph_b1[col1];
#pragma unroll
    for (int mt = 0; mt < 4; ++mt)
#pragma unroll
      for (int rg = 0; rg < 4; ++rg) {
        int row = mt * 16 + q * 4 + rg;
        XA[row * XS + col0] = f2b(silu(acc[mt][0][rg] + b0));
        XA[row * XS + col1] = f2b(silu(acc[mt][1][rg] + b1));
      }
  }
  BAR();

  // ---- ph layer 2 (no act) + residual from XB(featb) ----
#pragma unroll
  for (int mt = 0; mt < 4; ++mt) { acc[mt][0] = z4; acc[mt][1] = z4; }
  gemm2(XA, wq + 8 * 16384 + n0 * 128, c, q, acc);
  {
    float b0 = ph_b2[col0], b1 = ph_b2[col1];
#pragma unroll
    for (int mt = 0; mt < 4; ++mt)
#pragma unroll
      for (int rg = 0; rg < 4; ++rg) {
        int row = mt * 16 + q * 4 + rg;
        int nn = nb0 + row;
        if (nn < N_NODES) {
          size_t o = (size_t)nn * 128;
          float r0 = __uint_as_float(((uint)XB[row * XS + col0]) << 16);
          float r1 = __uint_as_float(((uint)XB[row * XS + col1]) << 16);
          outf[o + col0] = acc[mt][0][rg] + b0 + r0;
          outf[o + col1] = acc[mt][1][rg] + b1 + r1;
        }
      }
  }
  if (tid < 192) {
    int nl = tid / 3, cc = tid - nl * 3;
    int nn = nb0 + nl;
    if (nn < N_NODES)
      outv[nn * 3 + cc] = pos[nn * 3 + cc] + outv[nn * 3 + cc] * INV_AVG;
  }
}

// ---------------- launch ----------------
extern "C" void kernel_launch(void* const* d_in, const int* in_sizes, int n_in,
                              void* d_out, int out_size, void* d_ws, size_t ws_size,
                              hipStream_t stream) {
  const float* pos  = (const float*)d_in[0];
  const float* feat = (const float*)d_in[1];
  const float* pe_w0 = (const float*)d_in[2];
  const float* pe_b0 = (const float*)d_in[3];
  const float* pe_b1 = (const float*)d_in[5];
  const float* px_b0 = (const float*)d_in[7];
  const float* px_b1 = (const float*)d_in[9];
  const float* px_out_w = (const float*)d_in[10];
  const float* px_out_b = (const float*)d_in[11];
  const float* e_w = (const float*)d_in[12];
  const float* e_b = (const float*)d_in[13];
  const float* ph_b0 = (const float*)d_in[15];
  const float* ph_b1 = (const float*)d_in[17];
  const float* ph_b2 = (const float*)d_in[19];
  const int* snd = (const int*)d_in[20];
  const int* rcv = (const int*)d_in[21];
  ushort* wq = (ushort*)d_ws;
  ushort* featb = wq + FEATB_OFF;
  float* out = (float*)d_out;
  // after setup consumes feat, its buffer becomes the f16 m_i accumulator
  ushort* outm = (ushort*)d_in[1];

  PrepArgs a;
  a.src[0] = pe_w0;
  a.src[1] = pe_w0 + 128 * 128;
  a.src[2] = (const float*)d_in[4];               // pe_w1
  a.src[3] = (const float*)d_in[6];               // px_w0
  a.src[4] = (const float*)d_in[8];               // px_w1
  a.src[5] = (const float*)d_in[14];              // ph_w0 (m_i half)
  a.src[6] = (const float*)d_in[14] + 128 * 128;  // ph_w0 (feat half)
  a.src[7] = (const float*)d_in[16];              // ph_w1
  a.src[8] = (const float*)d_in[18];              // ph_w2

  // single setup launch: weight cvt + feat cvt + zero m_acc (aliasing, same-thread)
  // + zero outv
  setup_kernel<<<(N_NODES * 128) / 256, 256, 0, stream>>>(a, feat, wq, featb,
                                                          (uint*)outm, out);

  edge_kernel<<<N_EDGES / 64, 256, 0, stream>>>(
      pos, featb, snd, rcv, wq,
      pe_w0, pe_b0, pe_b1, px_b0, px_b1,
      px_out_w, px_out_b, e_w, e_b,
      out, outm);

  node_kernel<<<(N_NODES + 63) / 64, 256, 0, stream>>>(
      pos, featb, wq, outm, ph_b0, ph_b1, ph_b2,
      out, out + 60000);
}